// Round 7
// baseline (726.622 us; speedup 1.0000x reference)
//
#include <hip/hip_runtime.h>

#define BN_EPS 1e-5f

static inline size_t align_up(size_t x, size_t a) { return (x + a - 1) & ~(a - 1); }

// ---------------- histogram: float deg (sum ew) + int count per dst ----------------

__global__ void hist_kernel(const int* __restrict__ dst, const float* __restrict__ ew,
                            float* __restrict__ deg, int* __restrict__ cntc, int E) {
    int e = blockIdx.x * blockDim.x + threadIdx.x;
    if (e < E) {
        int d = dst[e];
        atomicAdd(&deg[d], ew[e]);
        atomicAdd(&cntc[d], 1);
    }
}

__global__ void dinv_kernel(float* deg, int N) {
    int i = blockIdx.x * blockDim.x + threadIdx.x;
    if (i < N) deg[i] = rsqrtf(deg[i] + 1.0f);   // +1 = self-loop weight
}

// ---------------- exclusive scan (3-phase) over cntc[N] -> rowptr/cursor ----------------

__global__ void scan1_kernel(const int* __restrict__ cnt, int* __restrict__ excl,
                             int* __restrict__ bsum, int N) {
    __shared__ int lds[256];
    int base = blockIdx.x * 1024;
    int t = threadIdx.x;
    int v[4]; int s = 0;
    #pragma unroll
    for (int j = 0; j < 4; ++j) {
        int idx = base + t * 4 + j;
        v[j] = (idx < N) ? cnt[idx] : 0;
        s += v[j];
    }
    lds[t] = s;
    __syncthreads();
    for (int off = 1; off < 256; off <<= 1) {
        int x = (t >= off) ? lds[t - off] : 0;
        __syncthreads();
        lds[t] += x;
        __syncthreads();
    }
    int run = lds[t] - s;
    #pragma unroll
    for (int j = 0; j < 4; ++j) {
        int idx = base + t * 4 + j;
        if (idx < N) excl[idx] = run;
        run += v[j];
    }
    if (t == 255) bsum[blockIdx.x] = lds[255];
}

__global__ void scan2_kernel(int* __restrict__ bsum, int nb) {
    __shared__ int lds[256];
    int t = threadIdx.x;
    int v = (t < nb) ? bsum[t] : 0;
    lds[t] = v;
    __syncthreads();
    for (int off = 1; off < 256; off <<= 1) {
        int x = (t >= off) ? lds[t - off] : 0;
        __syncthreads();
        lds[t] += x;
        __syncthreads();
    }
    if (t < nb) bsum[t] = lds[t] - v;
}

__global__ void scan3_kernel(const int* __restrict__ excl, const int* __restrict__ bsum,
                             int* __restrict__ rowptr, int* __restrict__ cursor, int N, int E) {
    int idx = blockIdx.x * blockDim.x + threadIdx.x;
    if (idx < N) {
        int v = excl[idx] + bsum[idx >> 10];
        rowptr[idx] = v;
        cursor[idx] = v;
    }
    if (idx == 0) rowptr[N] = E;
}

// ---------------- bucket edges by dst: edges[pos] = (src, norm) ----------------

__global__ void bucket_kernel(const int* __restrict__ src, const int* __restrict__ dst,
                              const float* __restrict__ ew, const float* __restrict__ dinv,
                              int* __restrict__ cursor, int2* __restrict__ edges, int E) {
    int e = blockIdx.x * blockDim.x + threadIdx.x;
    if (e >= E) return;
    int s = src[e], d = dst[e];
    float nrm = dinv[s] * ew[e] * dinv[d];
    int pos = atomicAdd(&cursor[d], 1);
    edges[pos] = make_int2(s, __float_as_int(nrm));
}

// ---------------- fp32 GEMM: Y[N x 128] = X[N x K] @ W[K x 128] ----------------
// 128 rows/block, 256 threads, 8x8 acc/thread. W staged in 64-k chunks (32 KB LDS
// -> ~5 blocks/CU vs R5's 64 KB -> 2 blocks, Occupancy 14% -> VALU starved).
// X read from global: 16 lanes/row share the address (HW broadcast), k-sequential.
// Col split cg*4 / 64+cg*4: 2-way bank aliasing = free (m136). unroll 1 on k loops
// (R3 post-mortem: aggressive unroll -> 256 VGPR -> scratch spills).

template<int K>
__launch_bounds__(256, 4)
__global__ void gemm_kernel(const float* __restrict__ X, const float* __restrict__ W,
                            float* __restrict__ Y, int N) {
    __shared__ float sW[64 * 128];   // 32 KB chunk
    int tid = threadIdx.x;

    int row0 = blockIdx.x * 128;
    int cg = tid & 15;
    int r  = tid >> 4;

    // clamped row pointers: OOB rows read row N-1 (valid, finite); stores guarded.
    const float* xp[8];
    #pragma unroll
    for (int i = 0; i < 8; ++i) {
        int row = row0 + r + 16 * i;
        if (row > N - 1) row = N - 1;
        xp[i] = &X[(size_t)row * K];
    }

    float acc[8][8];
    #pragma unroll
    for (int i = 0; i < 8; ++i)
        #pragma unroll
        for (int j = 0; j < 8; ++j) acc[i][j] = 0.f;

    #pragma unroll 1
    for (int c = 0; c < K; c += 64) {
        const int klen = (K - c < 64) ? (K - c) : 64;
        __syncthreads();   // prior chunk reads complete before overwrite
        for (int i = tid; i < klen * 32; i += 256)
            ((float4*)sW)[i] = ((const float4*)&W[(size_t)c * 128])[i];
        __syncthreads();

        #pragma unroll 1
        for (int kk = 0; kk < klen; kk += 4) {
            float4 xv[8];
            #pragma unroll
            for (int i = 0; i < 8; ++i)
                xv[i] = *((const float4*)(xp[i] + c + kk));
            #pragma unroll
            for (int j = 0; j < 4; ++j) {
                float4 w0 = *((const float4*)&sW[(kk + j) * 128 + cg * 4]);
                float4 w1 = *((const float4*)&sW[(kk + j) * 128 + 64 + cg * 4]);
                #pragma unroll
                for (int i = 0; i < 8; ++i) {
                    float xs = (j == 0) ? xv[i].x : (j == 1) ? xv[i].y
                             : (j == 2) ? xv[i].z : xv[i].w;
                    acc[i][0] += xs * w0.x; acc[i][1] += xs * w0.y;
                    acc[i][2] += xs * w0.z; acc[i][3] += xs * w0.w;
                    acc[i][4] += xs * w1.x; acc[i][5] += xs * w1.y;
                    acc[i][6] += xs * w1.z; acc[i][7] += xs * w1.w;
                }
            }
        }
    }

    #pragma unroll
    for (int i = 0; i < 8; ++i) {
        int row = row0 + r + 16 * i;
        if (row < N) {
            float* y = &Y[(size_t)row * 128];
            *((float4*)&y[cg * 4])      = make_float4(acc[i][0], acc[i][1], acc[i][2], acc[i][3]);
            *((float4*)&y[64 + cg * 4]) = make_float4(acc[i][4], acc[i][5], acc[i][6], acc[i][7]);
        }
    }
}

// ---------------- BN(eval) scale/shift precompute ----------------

__global__ void scaleshift_kernel(const float* __restrict__ gamma, const float* __restrict__ beta,
                                  const float* __restrict__ rm, const float* __restrict__ rv,
                                  const float* __restrict__ b,
                                  float* __restrict__ scale, float* __restrict__ shift) {
    int j = threadIdx.x;   // 128 threads
    float sc = gamma[j] * rsqrtf(rv[j] + BN_EPS);
    scale[j] = sc;
    shift[j] = beta[j] + (b[j] - rm[j]) * sc;
}

// ---------------- fused aggregation: CSR gather + self-loop + BN + ReLU ----------------
// one wave per dst node. Lanes >= m hold (src=node, w=0) padding -> safe loads,
// zero contribution; trip count rounded to x4 so each iteration issues 4
// INDEPENDENT H-loads (R5 post-mortem: serialized readlane->load->FMA chain).

__launch_bounds__(256)
__global__ void agg_kernel(const float* __restrict__ H, const int2* __restrict__ edges,
                           const int* __restrict__ rowptr, const float* __restrict__ dinv,
                           const float* __restrict__ scale, const float* __restrict__ shift,
                           float* __restrict__ out, int N) {
    int idx = blockIdx.x * blockDim.x + threadIdx.x;
    int node = idx >> 6, lane = idx & 63;
    if (node >= N) return;

    float d = dinv[node];
    float w0 = d * d;
    float2 h = ((const float2*)&H[(size_t)node * 128])[lane];
    float ax = h.x * w0, ay = h.y * w0;

    int beg = rowptr[node], end = rowptr[node + 1];
    for (int base = beg; base < end; base += 64) {
        int m = end - base; if (m > 64) m = 64;
        int2 pr = (lane < m) ? edges[base + lane] : make_int2(node, 0);
        int mr = (m + 3) & ~3;
        for (int j = 0; j < mr; j += 4) {
            int   s0 = __builtin_amdgcn_readlane(pr.x, j);
            int   s1 = __builtin_amdgcn_readlane(pr.x, j + 1);
            int   s2 = __builtin_amdgcn_readlane(pr.x, j + 2);
            int   s3 = __builtin_amdgcn_readlane(pr.x, j + 3);
            float w0e = __int_as_float(__builtin_amdgcn_readlane(pr.y, j));
            float w1e = __int_as_float(__builtin_amdgcn_readlane(pr.y, j + 1));
            float w2e = __int_as_float(__builtin_amdgcn_readlane(pr.y, j + 2));
            float w3e = __int_as_float(__builtin_amdgcn_readlane(pr.y, j + 3));
            float2 h0 = ((const float2*)&H[(size_t)s0 * 128])[lane];
            float2 h1 = ((const float2*)&H[(size_t)s1 * 128])[lane];
            float2 h2 = ((const float2*)&H[(size_t)s2 * 128])[lane];
            float2 h3 = ((const float2*)&H[(size_t)s3 * 128])[lane];
            ax += h0.x * w0e; ay += h0.y * w0e;
            ax += h1.x * w1e; ay += h1.y * w1e;
            ax += h2.x * w2e; ay += h2.y * w2e;
            ax += h3.x * w3e; ay += h3.y * w3e;
        }
    }

    float2 sc = ((const float2*)scale)[lane];
    float2 sh = ((const float2*)shift)[lane];
    float2 o;
    o.x = fmaxf(ax * sc.x + sh.x, 0.f);
    o.y = fmaxf(ay * sc.y + sh.y, 0.f);
    ((float2*)&out[(size_t)node * 128])[lane] = o;
}

// ---------------- pooling: graph boundaries + per-graph block reduction ----------------

__global__ void bounds_kernel(const int* __restrict__ batch, int* __restrict__ gstart,
                              int N, int G) {
    int i = blockIdx.x * blockDim.x + threadIdx.x;
    if (i >= N) return;
    int b = batch[i];
    int prev = (i == 0) ? -1 : batch[i - 1];
    for (int g = prev + 1; g <= b; ++g) gstart[g] = i;
    if (i == N - 1) {
        for (int g = b + 1; g <= G; ++g) gstart[g] = N;
    }
}

__launch_bounds__(256)
__global__ void pool2_kernel(const float* __restrict__ H, const int* __restrict__ gstart,
                             const float* __restrict__ Wout, const float* __restrict__ bout,
                             float* __restrict__ out, int G) {
    int g = blockIdx.x;
    int beg = gstart[g], end = gstart[g + 1];
    int t = threadIdx.x;
    int c = t & 127;
    int half = t >> 7;
    float acc = 0.f;
    for (int n = beg + half; n < end; n += 2)
        acc += H[(size_t)n * 128 + c];
    __shared__ float lds[256];
    lds[t] = acc * Wout[c];
    __syncthreads();
    if (t < 64) lds[t] = lds[t] + lds[t + 64] + lds[t + 128] + lds[t + 192];
    __syncthreads();
    if (t < 64) {
        float s = lds[t];
        #pragma unroll
        for (int off = 32; off > 0; off >>= 1) s += __shfl_down(s, off, 64);
        if (t == 0) {
            float cntf = (float)(end - beg);
            out[g] = s / fmaxf(cntf, 1.0f) + bout[0];
        }
    }
}

// ---------------- host launch ----------------

extern "C" void kernel_launch(void* const* d_in, const int* in_sizes, int n_in,
                              void* d_out, int out_size, void* d_ws, size_t ws_size,
                              hipStream_t stream) {
    const float* x     = (const float*)d_in[0];
    const int*   ei    = (const int*)d_in[1];
    const float* ew    = (const float*)d_in[2];
    const int*   batch = (const int*)d_in[3];
    const float* W0 = (const float*)d_in[4];
    const float* b0 = (const float*)d_in[5];
    const float* W1 = (const float*)d_in[6];
    const float* b1 = (const float*)d_in[7];
    const float* W2 = (const float*)d_in[8];
    const float* b2 = (const float*)d_in[9];
    const float* gamma = (const float*)d_in[10];
    const float* beta  = (const float*)d_in[11];
    const float* rmean = (const float*)d_in[12];
    const float* rvar  = (const float*)d_in[13];
    const float* Wout  = (const float*)d_in[14];
    const float* bout  = (const float*)d_in[15];

    const int E = in_sizes[2];
    const int N = in_sizes[3];
    const int D_IN = in_sizes[0] / N;   // 100
    const int G = out_size;

    const int* src = ei;
    const int* dst = ei + E;

    char* ws = (char*)d_ws;
    size_t off = 0;
    float* dinv  = (float*)(ws + off); off = align_up(off + (size_t)N * 4, 256);
    int* cntc    = (int*)(ws + off);   off = align_up(off + (size_t)N * 4, 256);
    int* excl    = (int*)(ws + off);   off = align_up(off + (size_t)N * 4, 256);
    int* rowptr  = (int*)(ws + off);   off = align_up(off + ((size_t)N + 1) * 4, 256);
    int* cursor  = (int*)(ws + off);   off = align_up(off + (size_t)N * 4, 256);
    int* bsum    = (int*)(ws + off);   off = align_up(off + 256 * 4, 256);
    int* gstart  = (int*)(ws + off);   off = align_up(off + ((size_t)G + 1) * 4, 256);
    int2* edges  = (int2*)(ws + off);  off = align_up(off + (size_t)E * 8, 256);
    float* buf0  = (float*)(ws + off); off = align_up(off + (size_t)N * 128 * 4, 256);
    float* buf1  = (float*)(ws + off); off = align_up(off + (size_t)N * 128 * 4, 256);
    float* scale = (float*)(ws + off); off = align_up(off + 128 * 4, 256);
    float* shift = (float*)(ws + off); off = align_up(off + 128 * 4, 256);
    (void)ws_size;

    hipMemsetAsync(dinv, 0, (size_t)N * 4, stream);
    hipMemsetAsync(cntc, 0, (size_t)N * 4, stream);

    const int tB = 256;
    hist_kernel<<<(E + tB - 1) / tB, tB, 0, stream>>>(dst, ew, dinv, cntc, E);
    dinv_kernel<<<(N + tB - 1) / tB, tB, 0, stream>>>(dinv, N);

    int nb = (N + 1023) / 1024;
    scan1_kernel<<<nb, 256, 0, stream>>>(cntc, excl, bsum, N);
    scan2_kernel<<<1, 256, 0, stream>>>(bsum, nb);
    scan3_kernel<<<(N + tB - 1) / tB, tB, 0, stream>>>(excl, bsum, rowptr, cursor, N, E);
    bucket_kernel<<<(E + tB - 1) / tB, tB, 0, stream>>>(src, dst, ew, dinv, cursor, edges, E);
    bounds_kernel<<<(N + tB - 1) / tB, tB, 0, stream>>>(batch, gstart, N, G);

    const float* Ws[3] = {W0, W1, W2};
    const float* bs[3] = {b0, b1, b2};

    long nthread_node = (long)N * 64;
    int blocks_node = (int)((nthread_node + tB - 1) / tB);
    int gemm_blocks = (N + 127) / 128;

    for (int l = 0; l < 3; ++l) {
        scaleshift_kernel<<<1, 128, 0, stream>>>(gamma + l * 128, beta + l * 128,
                                                 rmean + l * 128, rvar + l * 128,
                                                 bs[l], scale, shift);
        const float* in = (l == 0) ? x : buf1;
        if (l == 0) {
            if (D_IN == 100)
                gemm_kernel<100><<<gemm_blocks, 256, 0, stream>>>(in, Ws[l], buf0, N);
            else
                gemm_kernel<128><<<gemm_blocks, 256, 0, stream>>>(in, Ws[l], buf0, N);
        } else {
            gemm_kernel<128><<<gemm_blocks, 256, 0, stream>>>(in, Ws[l], buf0, N);
        }
        agg_kernel<<<blocks_node, tB, 0, stream>>>(buf0, edges, rowptr, dinv,
                                                   scale, shift, buf1, N);
    }

    pool2_kernel<<<G, 256, 0, stream>>>(buf1, gstart, Wout, bout, (float*)d_out, G);
}

// Round 8
// 571.148 us; speedup vs baseline: 1.2722x; 1.2722x over previous
//
#include <hip/hip_runtime.h>

#define BN_EPS 1e-5f

static inline size_t align_up(size_t x, size_t a) { return (x + a - 1) & ~(a - 1); }

// ---------------- histogram: float deg (sum ew) + int count per dst ----------------

__global__ void hist_kernel(const int* __restrict__ dst, const float* __restrict__ ew,
                            float* __restrict__ deg, int* __restrict__ cntc, int E) {
    int e = blockIdx.x * blockDim.x + threadIdx.x;
    if (e < E) {
        int d = dst[e];
        atomicAdd(&deg[d], ew[e]);
        atomicAdd(&cntc[d], 1);
    }
}

__global__ void dinv_kernel(float* deg, int N) {
    int i = blockIdx.x * blockDim.x + threadIdx.x;
    if (i < N) deg[i] = rsqrtf(deg[i] + 1.0f);   // +1 = self-loop weight
}

// ---------------- exclusive scan (3-phase) over cntc[N] -> rowptr/cursor ----------------

__global__ void scan1_kernel(const int* __restrict__ cnt, int* __restrict__ excl,
                             int* __restrict__ bsum, int N) {
    __shared__ int lds[256];
    int base = blockIdx.x * 1024;
    int t = threadIdx.x;
    int v[4]; int s = 0;
    #pragma unroll
    for (int j = 0; j < 4; ++j) {
        int idx = base + t * 4 + j;
        v[j] = (idx < N) ? cnt[idx] : 0;
        s += v[j];
    }
    lds[t] = s;
    __syncthreads();
    for (int off = 1; off < 256; off <<= 1) {
        int x = (t >= off) ? lds[t - off] : 0;
        __syncthreads();
        lds[t] += x;
        __syncthreads();
    }
    int run = lds[t] - s;
    #pragma unroll
    for (int j = 0; j < 4; ++j) {
        int idx = base + t * 4 + j;
        if (idx < N) excl[idx] = run;
        run += v[j];
    }
    if (t == 255) bsum[blockIdx.x] = lds[255];
}

__global__ void scan2_kernel(int* __restrict__ bsum, int nb) {
    __shared__ int lds[256];
    int t = threadIdx.x;
    int v = (t < nb) ? bsum[t] : 0;
    lds[t] = v;
    __syncthreads();
    for (int off = 1; off < 256; off <<= 1) {
        int x = (t >= off) ? lds[t - off] : 0;
        __syncthreads();
        lds[t] += x;
        __syncthreads();
    }
    if (t < nb) bsum[t] = lds[t] - v;
}

__global__ void scan3_kernel(const int* __restrict__ excl, const int* __restrict__ bsum,
                             int* __restrict__ rowptr, int* __restrict__ cursor, int N, int E) {
    int idx = blockIdx.x * blockDim.x + threadIdx.x;
    if (idx < N) {
        int v = excl[idx] + bsum[idx >> 10];
        rowptr[idx] = v;
        cursor[idx] = v;
    }
    if (idx == 0) rowptr[N] = E;
}

// ---------------- bucket edges by dst: edges[pos] = (src, norm) ----------------

__global__ void bucket_kernel(const int* __restrict__ src, const int* __restrict__ dst,
                              const float* __restrict__ ew, const float* __restrict__ dinv,
                              int* __restrict__ cursor, int2* __restrict__ edges, int E) {
    int e = blockIdx.x * blockDim.x + threadIdx.x;
    if (e >= E) return;
    int s = src[e], d = dst[e];
    float nrm = dinv[s] * ew[e] * dinv[d];
    int pos = atomicAdd(&cursor[d], 1);
    edges[pos] = make_int2(s, __float_as_int(nrm));
}

// ---------------- fp32 GEMM: Y[N x 128] = X[N x K] @ W[K x 128] ----------------
// 128 rows/block, 256 threads, 8x8 acc/thread. W staged in 64-k chunks (32 KB LDS
// -> 5 blocks/CU). X read from global: 16 lanes/row share the address (HW
// broadcast), k-sequential -> L1/L2 resident.
// launch_bounds MUST be (256,2): R6 post-mortem — minWaves=4 made the allocator
// jump to the 8-waves bucket (64 VGPR) by SPILLING the 64-reg accumulator
// (WRITE_SIZE 50->178 MB, dur 2x). (256,2) gives 88-110 VGPR, no spill (R5),
// and occupancy is then VGPR/LDS-limited at ~4-5 waves/EU.

template<int K>
__launch_bounds__(256, 2)
__global__ void gemm_kernel(const float* __restrict__ X, const float* __restrict__ W,
                            float* __restrict__ Y, int N) {
    __shared__ float sW[64 * 128];   // 32 KB chunk
    int tid = threadIdx.x;

    int row0 = blockIdx.x * 128;
    int cg = tid & 15;
    int r  = tid >> 4;

    // clamped row pointers: OOB rows read row N-1 (valid, finite); stores guarded.
    const float* xp[8];
    #pragma unroll
    for (int i = 0; i < 8; ++i) {
        int row = row0 + r + 16 * i;
        if (row > N - 1) row = N - 1;
        xp[i] = &X[(size_t)row * K];
    }

    float acc[8][8];
    #pragma unroll
    for (int i = 0; i < 8; ++i)
        #pragma unroll
        for (int j = 0; j < 8; ++j) acc[i][j] = 0.f;

    #pragma unroll 1
    for (int c = 0; c < K; c += 64) {
        const int klen = (K - c < 64) ? (K - c) : 64;
        __syncthreads();   // prior chunk reads complete before overwrite
        for (int i = tid; i < klen * 32; i += 256)
            ((float4*)sW)[i] = ((const float4*)&W[(size_t)c * 128])[i];
        __syncthreads();

        #pragma unroll 1
        for (int kk = 0; kk < klen; kk += 4) {
            float4 xv[8];
            #pragma unroll
            for (int i = 0; i < 8; ++i)
                xv[i] = *((const float4*)(xp[i] + c + kk));
            #pragma unroll
            for (int j = 0; j < 4; ++j) {
                float4 w0 = *((const float4*)&sW[(kk + j) * 128 + cg * 4]);
                float4 w1 = *((const float4*)&sW[(kk + j) * 128 + 64 + cg * 4]);
                #pragma unroll
                for (int i = 0; i < 8; ++i) {
                    float xs = (j == 0) ? xv[i].x : (j == 1) ? xv[i].y
                             : (j == 2) ? xv[i].z : xv[i].w;
                    acc[i][0] += xs * w0.x; acc[i][1] += xs * w0.y;
                    acc[i][2] += xs * w0.z; acc[i][3] += xs * w0.w;
                    acc[i][4] += xs * w1.x; acc[i][5] += xs * w1.y;
                    acc[i][6] += xs * w1.z; acc[i][7] += xs * w1.w;
                }
            }
        }
    }

    #pragma unroll
    for (int i = 0; i < 8; ++i) {
        int row = row0 + r + 16 * i;
        if (row < N) {
            float* y = &Y[(size_t)row * 128];
            *((float4*)&y[cg * 4])      = make_float4(acc[i][0], acc[i][1], acc[i][2], acc[i][3]);
            *((float4*)&y[64 + cg * 4]) = make_float4(acc[i][4], acc[i][5], acc[i][6], acc[i][7]);
        }
    }
}

// ---------------- BN(eval) scale/shift precompute ----------------

__global__ void scaleshift_kernel(const float* __restrict__ gamma, const float* __restrict__ beta,
                                  const float* __restrict__ rm, const float* __restrict__ rv,
                                  const float* __restrict__ b,
                                  float* __restrict__ scale, float* __restrict__ shift) {
    int j = threadIdx.x;   // 128 threads
    float sc = gamma[j] * rsqrtf(rv[j] + BN_EPS);
    scale[j] = sc;
    shift[j] = beta[j] + (b[j] - rm[j]) * sc;
}

// ---------------- fused aggregation: CSR gather + self-loop + BN + ReLU ----------------
// one wave per dst node. Lanes >= m hold (src=node, w=0) padding -> safe loads,
// zero contribution; trip count rounded to x4 so each iteration issues 4
// INDEPENDENT H-loads (R6: this cut agg time ~25%/dispatch — keep).

__launch_bounds__(256)
__global__ void agg_kernel(const float* __restrict__ H, const int2* __restrict__ edges,
                           const int* __restrict__ rowptr, const float* __restrict__ dinv,
                           const float* __restrict__ scale, const float* __restrict__ shift,
                           float* __restrict__ out, int N) {
    int idx = blockIdx.x * blockDim.x + threadIdx.x;
    int node = idx >> 6, lane = idx & 63;
    if (node >= N) return;

    float d = dinv[node];
    float w0 = d * d;
    float2 h = ((const float2*)&H[(size_t)node * 128])[lane];
    float ax = h.x * w0, ay = h.y * w0;

    int beg = rowptr[node], end = rowptr[node + 1];
    for (int base = beg; base < end; base += 64) {
        int m = end - base; if (m > 64) m = 64;
        int2 pr = (lane < m) ? edges[base + lane] : make_int2(node, 0);
        int mr = (m + 3) & ~3;
        for (int j = 0; j < mr; j += 4) {
            int   s0 = __builtin_amdgcn_readlane(pr.x, j);
            int   s1 = __builtin_amdgcn_readlane(pr.x, j + 1);
            int   s2 = __builtin_amdgcn_readlane(pr.x, j + 2);
            int   s3 = __builtin_amdgcn_readlane(pr.x, j + 3);
            float w0e = __int_as_float(__builtin_amdgcn_readlane(pr.y, j));
            float w1e = __int_as_float(__builtin_amdgcn_readlane(pr.y, j + 1));
            float w2e = __int_as_float(__builtin_amdgcn_readlane(pr.y, j + 2));
            float w3e = __int_as_float(__builtin_amdgcn_readlane(pr.y, j + 3));
            float2 h0 = ((const float2*)&H[(size_t)s0 * 128])[lane];
            float2 h1 = ((const float2*)&H[(size_t)s1 * 128])[lane];
            float2 h2 = ((const float2*)&H[(size_t)s2 * 128])[lane];
            float2 h3 = ((const float2*)&H[(size_t)s3 * 128])[lane];
            ax += h0.x * w0e; ay += h0.y * w0e;
            ax += h1.x * w1e; ay += h1.y * w1e;
            ax += h2.x * w2e; ay += h2.y * w2e;
            ax += h3.x * w3e; ay += h3.y * w3e;
        }
    }

    float2 sc = ((const float2*)scale)[lane];
    float2 sh = ((const float2*)shift)[lane];
    float2 o;
    o.x = fmaxf(ax * sc.x + sh.x, 0.f);
    o.y = fmaxf(ay * sc.y + sh.y, 0.f);
    ((float2*)&out[(size_t)node * 128])[lane] = o;
}

// ---------------- pooling: graph boundaries + per-graph block reduction ----------------

__global__ void bounds_kernel(const int* __restrict__ batch, int* __restrict__ gstart,
                              int N, int G) {
    int i = blockIdx.x * blockDim.x + threadIdx.x;
    if (i >= N) return;
    int b = batch[i];
    int prev = (i == 0) ? -1 : batch[i - 1];
    for (int g = prev + 1; g <= b; ++g) gstart[g] = i;
    if (i == N - 1) {
        for (int g = b + 1; g <= G; ++g) gstart[g] = N;
    }
}

__launch_bounds__(256)
__global__ void pool2_kernel(const float* __restrict__ H, const int* __restrict__ gstart,
                             const float* __restrict__ Wout, const float* __restrict__ bout,
                             float* __restrict__ out, int G) {
    int g = blockIdx.x;
    int beg = gstart[g], end = gstart[g + 1];
    int t = threadIdx.x;
    int c = t & 127;
    int half = t >> 7;
    float acc = 0.f;
    for (int n = beg + half; n < end; n += 2)
        acc += H[(size_t)n * 128 + c];
    __shared__ float lds[256];
    lds[t] = acc * Wout[c];
    __syncthreads();
    if (t < 64) lds[t] = lds[t] + lds[t + 64] + lds[t + 128] + lds[t + 192];
    __syncthreads();
    if (t < 64) {
        float s = lds[t];
        #pragma unroll
        for (int off = 32; off > 0; off >>= 1) s += __shfl_down(s, off, 64);
        if (t == 0) {
            float cntf = (float)(end - beg);
            out[g] = s / fmaxf(cntf, 1.0f) + bout[0];
        }
    }
}

// ---------------- host launch ----------------

extern "C" void kernel_launch(void* const* d_in, const int* in_sizes, int n_in,
                              void* d_out, int out_size, void* d_ws, size_t ws_size,
                              hipStream_t stream) {
    const float* x     = (const float*)d_in[0];
    const int*   ei    = (const int*)d_in[1];
    const float* ew    = (const float*)d_in[2];
    const int*   batch = (const int*)d_in[3];
    const float* W0 = (const float*)d_in[4];
    const float* b0 = (const float*)d_in[5];
    const float* W1 = (const float*)d_in[6];
    const float* b1 = (const float*)d_in[7];
    const float* W2 = (const float*)d_in[8];
    const float* b2 = (const float*)d_in[9];
    const float* gamma = (const float*)d_in[10];
    const float* beta  = (const float*)d_in[11];
    const float* rmean = (const float*)d_in[12];
    const float* rvar  = (const float*)d_in[13];
    const float* Wout  = (const float*)d_in[14];
    const float* bout  = (const float*)d_in[15];

    const int E = in_sizes[2];
    const int N = in_sizes[3];
    const int D_IN = in_sizes[0] / N;   // 100
    const int G = out_size;

    const int* src = ei;
    const int* dst = ei + E;

    char* ws = (char*)d_ws;
    size_t off = 0;
    float* dinv  = (float*)(ws + off); off = align_up(off + (size_t)N * 4, 256);
    int* cntc    = (int*)(ws + off);   off = align_up(off + (size_t)N * 4, 256);
    int* excl    = (int*)(ws + off);   off = align_up(off + (size_t)N * 4, 256);
    int* rowptr  = (int*)(ws + off);   off = align_up(off + ((size_t)N + 1) * 4, 256);
    int* cursor  = (int*)(ws + off);   off = align_up(off + (size_t)N * 4, 256);
    int* bsum    = (int*)(ws + off);   off = align_up(off + 256 * 4, 256);
    int* gstart  = (int*)(ws + off);   off = align_up(off + ((size_t)G + 1) * 4, 256);
    int2* edges  = (int2*)(ws + off);  off = align_up(off + (size_t)E * 8, 256);
    float* buf0  = (float*)(ws + off); off = align_up(off + (size_t)N * 128 * 4, 256);
    float* buf1  = (float*)(ws + off); off = align_up(off + (size_t)N * 128 * 4, 256);
    float* scale = (float*)(ws + off); off = align_up(off + 128 * 4, 256);
    float* shift = (float*)(ws + off); off = align_up(off + 128 * 4, 256);
    (void)ws_size;

    hipMemsetAsync(dinv, 0, (size_t)N * 4, stream);
    hipMemsetAsync(cntc, 0, (size_t)N * 4, stream);

    const int tB = 256;
    hist_kernel<<<(E + tB - 1) / tB, tB, 0, stream>>>(dst, ew, dinv, cntc, E);
    dinv_kernel<<<(N + tB - 1) / tB, tB, 0, stream>>>(dinv, N);

    int nb = (N + 1023) / 1024;
    scan1_kernel<<<nb, 256, 0, stream>>>(cntc, excl, bsum, N);
    scan2_kernel<<<1, 256, 0, stream>>>(bsum, nb);
    scan3_kernel<<<(N + tB - 1) / tB, tB, 0, stream>>>(excl, bsum, rowptr, cursor, N, E);
    bucket_kernel<<<(E + tB - 1) / tB, tB, 0, stream>>>(src, dst, ew, dinv, cursor, edges, E);
    bounds_kernel<<<(N + tB - 1) / tB, tB, 0, stream>>>(batch, gstart, N, G);

    const float* Ws[3] = {W0, W1, W2};
    const float* bs[3] = {b0, b1, b2};

    long nthread_node = (long)N * 64;
    int blocks_node = (int)((nthread_node + tB - 1) / tB);
    int gemm_blocks = (N + 127) / 128;

    for (int l = 0; l < 3; ++l) {
        scaleshift_kernel<<<1, 128, 0, stream>>>(gamma + l * 128, beta + l * 128,
                                                 rmean + l * 128, rvar + l * 128,
                                                 bs[l], scale, shift);
        const float* in = (l == 0) ? x : buf1;
        if (l == 0) {
            if (D_IN == 100)
                gemm_kernel<100><<<gemm_blocks, 256, 0, stream>>>(in, Ws[l], buf0, N);
            else
                gemm_kernel<128><<<gemm_blocks, 256, 0, stream>>>(in, Ws[l], buf0, N);
        } else {
            gemm_kernel<128><<<gemm_blocks, 256, 0, stream>>>(in, Ws[l], buf0, N);
        }
        agg_kernel<<<blocks_node, tB, 0, stream>>>(buf0, edges, rowptr, dinv,
                                                   scale, shift, buf1, N);
    }

    pool2_kernel<<<G, 256, 0, stream>>>(buf1, gstart, Wout, bout, (float*)d_out, G);
}